// Round 2
// baseline (62.200 us; speedup 1.0000x reference)
//
#include <hip/hip_runtime.h>

// SConv2d with MAJ-gate tree (MAJ_DIM=3), N=8, C_IN=3, C_OUT=64, H=W=64, 3x3 conv s1 p1.
// maj3(a,b,c) = (a+b+c - abc)/2  (closed form of the combinatorial reference; verified R1).
//   L1 (kernel width j):  U = (w0x0 + w1x1 + w2x2) - (w0x0)(w1x1)(w2x2)   [= 2*m1]
//   L2 (kernel height i): m2 = 0.25*(Ua+Ub+Uc) - 0.0625*Ua*Ub*Uc          [0.5 of L1 folded in]
//   L3 (channels c):      m3 = 0.5*((a+b+d) - a*b*d)
//
// R2: grid 2048 blocks (channel-quartered), 4 channels/thread.
// R3: weights via wave-uniform s_load (scalar cache) — neutral, kept (frees LDS).
// R4: LDS/barrier structure deleted. A wave's 64 lanes ARE one output row, so the
//     horizontal taps (w-1, w, w+1) are lane-neighbor values: 9 coalesced global row
//     loads + __shfl_up/__shfl_down with edge masks (row edges == conv zero-pad).
//     Vertical pad rows are a wave-uniform branch (load skipped). No staging loop,
//     no div/mod, no ds_write/ds_read, no __syncthreads — waves are independent and
//     free-running, so occupancy can actually hide the post-poison cold-cache latency.

#define NC_OUT 64

__global__ __launch_bounds__(256, 8) void sconv_maj_kernel(
    const float* __restrict__ x,      // [8,3,64,64]
    const float* __restrict__ wgt,    // [64,3,3,3] -> flat [64,27]
    float* __restrict__ out)          // [8,64,64,64]
{
    const int bid = blockIdx.x;
    const int q   = bid & 3;            // channel quarter: channels q*16 .. q*16+15
    const int h   = (bid >> 2) & 63;    // output row
    const int n   = bid >> 8;           // image index
    const int tid = threadIdx.x;

    const int w  = tid & 63;                                  // output col (coalesced)
    const int su = __builtin_amdgcn_readfirstlane(tid >> 6);  // subgroup, forced SGPR

    // ---- taps straight from global + lane shifts (no LDS, no barrier) ----
    float xa[9], xb[9], xd[9];
    #pragma unroll
    for (int c = 0; c < 3; ++c) {
        #pragma unroll
        for (int r = 0; r < 3; ++r) {
            const int g  = c * 3 + r;
            const int gh = h - 1 + r;                 // wave-uniform
            float v = 0.0f;
            if ((unsigned)gh < 64u)                   // uniform branch: pad rows skip load
                v = x[((n * 3 + c) * 64 + gh) * 64 + w];
            xb[g] = v;
            const float up = __shfl_up(v, 1);         // lane w-1's value
            const float dn = __shfl_down(v, 1);       // lane w+1's value
            xa[g] = (w == 0)  ? 0.0f : up;            // left edge == zero pad
            xd[g] = (w == 63) ? 0.0f : dn;            // right edge == zero pad
        }
    }

    // ---- 4 output channels per thread; weights via uniform s_load ----
    const int co0 = q * 16 + su * 4;
    #pragma unroll
    for (int t = 0; t < 4; ++t) {
        const int co = co0 + t;                 // wave-uniform
        const float* wr = wgt + co * 27;        // -> s_load (scalar cache)
        float m2[3];
        #pragma unroll
        for (int c = 0; c < 3; ++c) {
            float U[3];
            #pragma unroll
            for (int i = 0; i < 3; ++i) {
                const int g = c * 3 + i;
                const float ap = wr[g * 3 + 0] * xa[g];
                const float bp = wr[g * 3 + 1] * xb[g];
                const float dp = wr[g * 3 + 2] * xd[g];
                U[i] = (ap + bp + dp) - ap * bp * dp;     // 2*maj3(ap,bp,dp)
            }
            m2[c] = fmaf(0.25f, U[0] + U[1] + U[2], -0.0625f * (U[0] * U[1] * U[2]));
        }
        const float a = m2[0], b = m2[1], d = m2[2];
        const float o = 0.5f * ((a + b + d) - a * b * d);
        out[((n * NC_OUT + co) * 64 + h) * 64 + w] = o;
    }
}

extern "C" void kernel_launch(void* const* d_in, const int* in_sizes, int n_in,
                              void* d_out, int out_size, void* d_ws, size_t ws_size,
                              hipStream_t stream) {
    const float* x   = (const float*)d_in[0];   // 8*3*64*64
    const float* wgt = (const float*)d_in[1];   // 64*3*3*3
    float* out = (float*)d_out;                 // 8*64*64*64
    // grid: (n, h, quarter): 8*64*4 = 2048 blocks
    sconv_maj_kernel<<<dim3(2048), dim3(256), 0, stream>>>(x, wgt, out);
}